// Round 7
// baseline (674.221 us; speedup 1.0000x reference)
//
#include <hip/hip_runtime.h>

#define N_NODES 50000
#define N_EDGES 800000
#define SCAN_B 196   // ceil(50000/256)

typedef short bf16x8 __attribute__((ext_vector_type(8)));
typedef short bf16x4 __attribute__((ext_vector_type(4)));
typedef float f32x4 __attribute__((ext_vector_type(4)));

#define GLDS16(g, l)                                                  \
  __builtin_amdgcn_global_load_lds(                                   \
      (const __attribute__((address_space(1))) void*)(g),             \
      (__attribute__((address_space(3))) void*)(l), 16, 0, 0)

__device__ __forceinline__ unsigned short f2bf_rne(float x) {
  unsigned u = __float_as_uint(x);
  u += 0x7FFFu + ((u >> 16) & 1u);
  return (unsigned short)(u >> 16);
}

__device__ __forceinline__ void split2(float x, short& hi, short& lo) {
  unsigned u = __float_as_uint(x);
  unsigned short h = (unsigned short)(u >> 16);  // truncate to bf16
  float hf = __uint_as_float((unsigned)h << 16);
  float r = x - hf;
  unsigned short l = (unsigned short)(__float_as_uint(r) >> 16);
  hi = (short)h;
  lo = (short)l;
}

// ============================================================
// Counting sort by dst: hist -> 2-level exclusive scan -> scatter
// ============================================================
__global__ __launch_bounds__(256) void hist_k(const int* __restrict__ ei,
                                              int* __restrict__ cnt) {
  int e = blockIdx.x * 256 + threadIdx.x;
  if (e >= N_EDGES) return;
  atomicAdd(&cnt[ei[N_EDGES + e]], 1);
}

__global__ __launch_bounds__(256) void scan1(const int* __restrict__ cnt,
                                             int* __restrict__ offs,
                                             int* __restrict__ bsum) {
  __shared__ int sh[256];
  int t = threadIdx.x;
  int i = blockIdx.x * 256 + t;
  int v = (i < N_NODES) ? cnt[i] : 0;
  sh[t] = v;
  __syncthreads();
  for (int off = 1; off < 256; off <<= 1) {
    int add = (t >= off) ? sh[t - off] : 0;
    __syncthreads();
    sh[t] += add;
    __syncthreads();
  }
  if (i < N_NODES) offs[i] = sh[t] - v;  // exclusive
  if (t == 255) bsum[blockIdx.x] = sh[255];
}

__global__ __launch_bounds__(256) void scan2(const int* __restrict__ bsum,
                                             int* __restrict__ bofs) {
  __shared__ int sh[256];
  int t = threadIdx.x;
  int v = (t < SCAN_B) ? bsum[t] : 0;
  sh[t] = v;
  __syncthreads();
  for (int off = 1; off < 256; off <<= 1) {
    int add = (t >= off) ? sh[t - off] : 0;
    __syncthreads();
    sh[t] += add;
    __syncthreads();
  }
  if (t < SCAN_B) bofs[t] = sh[t] - v;
}

__global__ __launch_bounds__(256) void scan3(int* __restrict__ offs,
                                             const int* __restrict__ bofs) {
  int i = blockIdx.x * 256 + threadIdx.x;
  if (i < N_NODES) offs[i] += bofs[blockIdx.x];
  if (i == 0) offs[N_NODES] = N_EDGES;
}

__global__ __launch_bounds__(256) void scatter_k(const int* __restrict__ ei,
                                                 const int* __restrict__ offs,
                                                 int* __restrict__ cur,
                                                 int* __restrict__ ssort) {
  int e = blockIdx.x * 256 + threadIdx.x;
  if (e >= N_EDGES) return;
  int d = ei[N_EDGES + e];
  int p = offs[d] + atomicAdd(&cur[d], 1);
  ssort[p] = ei[e];
}

// ============================================================
// Pre-split BOTH weight matrices into bf16 hi/lo, MFMA-fragment
// layout, in one launch. chunk (kq, n)[j] = W[(kq*8+j)*Nn + n]
// ============================================================
__global__ __launch_bounds__(256) void wsplit_all(
    const float* __restrict__ W1, unsigned short* __restrict__ W1h,
    unsigned short* __restrict__ W1l,
    const float* __restrict__ W2, unsigned short* __restrict__ W2h,
    unsigned short* __restrict__ W2l) {
  int i = blockIdx.x * 256 + threadIdx.x;
  const float* W;
  unsigned short *Wh, *Wl;
  int Nn, c;
  if (i < 16384) {
    W = W1; Wh = W1h; Wl = W1l; Nn = 256; c = i;
  } else if (i < 16384 + 2048) {
    W = W2; Wh = W2h; Wl = W2l; Nn = 64; c = i - 16384;
  } else {
    return;
  }
  int kq = c / Nn;
  int n = c % Nn;
  alignas(16) short h[8], l[8];
#pragma unroll
  for (int j = 0; j < 8; ++j) {
    float v = W[(size_t)(kq * 8 + j) * Nn + n];
    split2(v, h[j], l[j]);
  }
  size_t dst = (size_t)c * 8;
  *(bf16x8*)&Wh[dst] = *(bf16x8*)h;
  *(bf16x8*)&Wl[dst] = *(bf16x8*)l;
}

// ============================================================
// GEMM1 fused (round-0 structure): h1b = bf16(x @ W1),
// asrc/adst = att dots. BM=128, BN=128. 4 blocks/CU occupancy is the
// latency-hiding mechanism — do NOT double-buffer (R1 regression).
// ============================================================
__global__ __launch_bounds__(256) void gemm1_fused(
    const float* __restrict__ A,
    const unsigned short* __restrict__ Bh_g, const unsigned short* __restrict__ Bl_g,
    const float* __restrict__ att_s, const float* __restrict__ att_d,
    unsigned short* __restrict__ h1b, float* __restrict__ asrc,
    float* __restrict__ adst, int M) {
  constexpr int K = 512, Nn = 256;
  constexpr int LDA = 40;
  __shared__ short Ah[128][LDA], Al[128][LDA];
  __shared__ short Bh[4 * 128 * 8], Bl[4 * 128 * 8];  // [quad][n_local][8]
  __shared__ float attLds[128][4];

  const int tid = threadIdx.x;
  const int wave = tid >> 6, lane = tid & 63;
  const int quad = lane >> 4, l16 = lane & 15;
  const int wm = (wave >> 1) * 64, wn = (wave & 1) * 64;
  const int rowBase = blockIdx.x * 128;
  const int colBase = blockIdx.y * 128;

  const int ra = tid >> 1, apart = (tid & 1) * 16;
  const int arow = min(rowBase + ra, M - 1);
  const float* aptr = A + (size_t)arow * K + apart;

  f32x4 acc[4][4] = {};

  for (int kc = 0; kc < K / 32; ++kc) {
    // ---- B tile: async global->LDS (4 chunks/thread: 2 hi + 2 lo) ----
#pragma unroll
    for (int inst = 0; inst < 2; ++inst) {
      int seq = inst * 256 + tid;
      int gq = seq >> 7, nl = seq & 127;
      size_t gsrc = (((size_t)kc * 4 + gq) * Nn + colBase + nl) * 8;
      GLDS16(Bh_g + gsrc, &Bh[seq * 8]);
      GLDS16(Bl_g + gsrc, &Bl[seq * 8]);
    }
    // ---- A tile: fp32 load, split, LDS store ----
    {
      alignas(16) short h[16], l[16];
      const float4* a4 = (const float4*)(aptr + kc * 32);
#pragma unroll
      for (int i = 0; i < 4; ++i) {
        float4 v = a4[i];
        split2(v.x, h[i * 4 + 0], l[i * 4 + 0]);
        split2(v.y, h[i * 4 + 1], l[i * 4 + 1]);
        split2(v.z, h[i * 4 + 2], l[i * 4 + 2]);
        split2(v.w, h[i * 4 + 3], l[i * 4 + 3]);
      }
      *(bf16x8*)&Ah[ra][apart]     = ((bf16x8*)h)[0];
      *(bf16x8*)&Ah[ra][apart + 8] = ((bf16x8*)h)[1];
      *(bf16x8*)&Al[ra][apart]     = ((bf16x8*)l)[0];
      *(bf16x8*)&Al[ra][apart + 8] = ((bf16x8*)l)[1];
    }
    __syncthreads();
    // ---- fragments + MFMA ----
    bf16x8 afh[4], afl[4], bfh[4], bfl[4];
#pragma unroll
    for (int mt = 0; mt < 4; ++mt) {
      afh[mt] = *(const bf16x8*)&Ah[wm + mt * 16 + l16][quad * 8];
      afl[mt] = *(const bf16x8*)&Al[wm + mt * 16 + l16][quad * 8];
    }
#pragma unroll
    for (int nt = 0; nt < 4; ++nt) {
      int bi = ((quad << 7) + wn + nt * 16 + l16) * 8;
      bfh[nt] = *(const bf16x8*)&Bh[bi];
      bfl[nt] = *(const bf16x8*)&Bl[bi];
    }
#pragma unroll
    for (int mt = 0; mt < 4; ++mt)
#pragma unroll
      for (int nt = 0; nt < 4; ++nt) {
        acc[mt][nt] = __builtin_amdgcn_mfma_f32_16x16x32_bf16(afh[mt], bfh[nt], acc[mt][nt], 0, 0, 0);
        acc[mt][nt] = __builtin_amdgcn_mfma_f32_16x16x32_bf16(afh[mt], bfl[nt], acc[mt][nt], 0, 0, 0);
        acc[mt][nt] = __builtin_amdgcn_mfma_f32_16x16x32_bf16(afl[mt], bfh[nt], acc[mt][nt], 0, 0, 0);
      }
    __syncthreads();
  }

  // ---- epilogue: bf16 store + fused attention dots ----
  float asw[4], adw[4];
#pragma unroll
  for (int nt = 0; nt < 4; ++nt) {
    int c = colBase + wn + nt * 16 + l16;
    asw[nt] = att_s[c];
    adw[nt] = att_d[c];
  }
#pragma unroll
  for (int mt = 0; mt < 4; ++mt) {
    int rl = wm + mt * 16 + quad * 4;
#pragma unroll
    for (int reg = 0; reg < 4; ++reg) {
      int r = rowBase + rl + reg;
      float s = 0.f, dd = 0.f;
#pragma unroll
      for (int nt = 0; nt < 4; ++nt) {
        float v = acc[mt][nt][reg];
        s += v * asw[nt];
        dd += v * adw[nt];
        if (r < M) {
          int c = colBase + wn + nt * 16 + l16;
          h1b[(size_t)r * Nn + c] = f2bf_rne(v);
        }
      }
#pragma unroll
      for (int off = 1; off < 16; off <<= 1) {
        s += __shfl_xor(s, off);
        dd += __shfl_xor(dd, off);
      }
      if (l16 == 0) {
        attLds[rl + reg][(wn >> 6) * 2 + 0] = s;
        attLds[rl + reg][(wn >> 6) * 2 + 1] = dd;
      }
    }
  }
  __syncthreads();
  if (tid < 128) {
    int r = rowBase + tid;
    if (r < M) {
      int hb = colBase >> 6;  // 0 or 2
      asrc[r * 4 + hb + 0] = attLds[tid][0];
      adst[r * 4 + hb + 0] = attLds[tid][1];
      asrc[r * 4 + hb + 1] = attLds[tid][2];
      adst[r * 4 + hb + 1] = attLds[tid][3];
    }
  }
}

// ============================================================
// GEMM2 fused, v2: BM=64 -> grid 782 blocks (~3/CU) instead of 391
// (1.5/CU). gemm2 was occupancy-starved: only block-level TLP hides
// the 2-barrier-per-kc stage stall (R1 lesson), and with half the
// blocks of gemm1 it had none. Same B path, same 3-pass hi/lo MFMA;
// each wave owns 16 rows (acc[4]).
// ============================================================
__global__ __launch_bounds__(256) void gemm2_fused(
    const float* __restrict__ A,
    const unsigned short* __restrict__ Bh_g, const unsigned short* __restrict__ Bl_g,
    const float* __restrict__ att_s, const float* __restrict__ att_d,
    unsigned short* __restrict__ h2b, float* __restrict__ asrc,
    float* __restrict__ adst, int M) {
  constexpr int K = 256, Nn = 64;
  constexpr int LDA = 40;
  __shared__ short Ah[64][LDA], Al[64][LDA];
  __shared__ short Bh[4 * 64 * 8], Bl[4 * 64 * 8];  // [quad][n][8]
  __shared__ float attLds[64][2];

  const int tid = threadIdx.x;
  const int wave = tid >> 6, lane = tid & 63;
  const int quad = lane >> 4, l16 = lane & 15;
  const int wm = wave * 16;
  const int rowBase = blockIdx.x * 64;

  const int ra = tid >> 2, apart = (tid & 3) * 8;
  const int arow = min(rowBase + ra, M - 1);
  const float* aptr = A + (size_t)arow * K + apart;

  f32x4 acc[4] = {};

  for (int kc = 0; kc < K / 32; ++kc) {
    {
      size_t gsrc = (((size_t)kc * 4) * Nn) * 8 + (size_t)tid * 8;
      GLDS16(Bh_g + gsrc, &Bh[tid * 8]);
      GLDS16(Bl_g + gsrc, &Bl[tid * 8]);
    }
    {
      alignas(16) short h[8], l[8];
      const float4* a4 = (const float4*)(aptr + kc * 32);
#pragma unroll
      for (int i = 0; i < 2; ++i) {
        float4 v = a4[i];
        split2(v.x, h[i * 4 + 0], l[i * 4 + 0]);
        split2(v.y, h[i * 4 + 1], l[i * 4 + 1]);
        split2(v.z, h[i * 4 + 2], l[i * 4 + 2]);
        split2(v.w, h[i * 4 + 3], l[i * 4 + 3]);
      }
      *(bf16x8*)&Ah[ra][apart] = *(bf16x8*)h;
      *(bf16x8*)&Al[ra][apart] = *(bf16x8*)l;
    }
    __syncthreads();
    bf16x8 afh, afl, bfh[4], bfl[4];
    afh = *(const bf16x8*)&Ah[wm + l16][quad * 8];
    afl = *(const bf16x8*)&Al[wm + l16][quad * 8];
#pragma unroll
    for (int nt = 0; nt < 4; ++nt) {
      int bi = ((quad << 6) + nt * 16 + l16) * 8;
      bfh[nt] = *(const bf16x8*)&Bh[bi];
      bfl[nt] = *(const bf16x8*)&Bl[bi];
    }
#pragma unroll
    for (int nt = 0; nt < 4; ++nt) {
      acc[nt] = __builtin_amdgcn_mfma_f32_16x16x32_bf16(afh, bfh[nt], acc[nt], 0, 0, 0);
      acc[nt] = __builtin_amdgcn_mfma_f32_16x16x32_bf16(afh, bfl[nt], acc[nt], 0, 0, 0);
      acc[nt] = __builtin_amdgcn_mfma_f32_16x16x32_bf16(afl, bfh[nt], acc[nt], 0, 0, 0);
    }
    __syncthreads();
  }

  float asw[4], adw[4];
#pragma unroll
  for (int nt = 0; nt < 4; ++nt) {
    int c = nt * 16 + l16;
    asw[nt] = att_s[c];
    adw[nt] = att_d[c];
  }
  {
    int rl = wm + quad * 4;
#pragma unroll
    for (int reg = 0; reg < 4; ++reg) {
      int r = rowBase + rl + reg;
      float s = 0.f, dd = 0.f;
#pragma unroll
      for (int nt = 0; nt < 4; ++nt) {
        float v = acc[nt][reg];
        s += v * asw[nt];
        dd += v * adw[nt];
        if (r < M) {
          int c = nt * 16 + l16;
          h2b[(size_t)r * Nn + c] = f2bf_rne(v);
        }
      }
#pragma unroll
      for (int off = 1; off < 16; off <<= 1) {
        s += __shfl_xor(s, off);
        dd += __shfl_xor(dd, off);
      }
      if (l16 == 0) {
        attLds[rl + reg][0] = s;
        attLds[rl + reg][1] = dd;
      }
    }
  }
  __syncthreads();
  if (tid < 64) {
    int r = rowBase + tid;
    if (r < M) {
      asrc[r] = attLds[tid][0];
      adst[r] = attLds[tid][1];
    }
  }
}

// ============================================================
// Fused softmax + aggregation, layer 1 (H=4, C=64).
// v4 (reverted to): one dst per 32-thread group, zero LDS/barriers,
// depth-3 reg pipeline. Measured 91 µs — at the random-512B-gather
// fabric ceiling (R5/R6: three pipeline schedules all converge here).
// ============================================================
__global__ __launch_bounds__(256) void agg_l1(
    const int* __restrict__ offs, const int* __restrict__ ssort,
    const float* __restrict__ asrc, const float* __restrict__ adst,
    const unsigned short* __restrict__ h1b, const float* __restrict__ b1,
    float* __restrict__ outp, int n_nodes) {
  const int t = threadIdx.x;
  const int g = t >> 5, lt = t & 31;   // group 0..7, lane-in-group 0..31
  const int d = blockIdx.x * 8 + g;
  if (d >= n_nodes) return;
  const int h = lt >> 3;               // head of this lane's 8 features
  const int row0 = offs[d], row1 = offs[d + 1];
  const float ad = adst[d * 4 + h];
  float acc[8] = {};
  float denom = 0.f;
  const int m = row1 - row0;

  if (m > 0) {
    const int last = row1 - 1;
    // ---- prologue: 3 rows in flight ----
    int s0 = ssort[row0];
    int s1 = ssort[min(row0 + 1, last)];
    int s2 = ssort[min(row0 + 2, last)];
    int s3 = ssort[min(row0 + 3, last)];
    float a0 = asrc[s0 * 4 + h];
    float a1 = asrc[s1 * 4 + h];
    float a2 = asrc[s2 * 4 + h];
    bf16x8 p0 = *(const bf16x8*)&h1b[(size_t)s0 * 256 + lt * 8];
    bf16x8 p1 = *(const bf16x8*)&h1b[(size_t)s1 * 256 + lt * 8];
    bf16x8 p2 = *(const bf16x8*)&h1b[(size_t)s2 * 256 + lt * 8];
    for (int j = 0; j < m; ++j) {
      // ---- issue loads for j+3 (clamped; tail re-reads last row) ----
      int sN = ssort[min(row0 + j + 4, last)];
      float aN = asrc[s3 * 4 + h];
      bf16x8 pN = *(const bf16x8*)&h1b[(size_t)s3 * 256 + lt * 8];
      // ---- compute edge j ----
      float sc = a0 + ad;
      sc = sc > 0.f ? sc : 0.2f * sc;
      float ex = __expf(sc);
#pragma unroll
      for (int k = 0; k < 8; ++k) {
        float f = __uint_as_float((unsigned)(unsigned short)p0[k] << 16);
        acc[k] += f * ex;
      }
      denom += ex;
      // ---- rotate (static names only) ----
      s3 = sN;
      a0 = a1; a1 = a2; a2 = aN;
      p0 = p1; p1 = p2; p2 = pN;
    }
  }
  float inv = denom > 0.f ? 1.f / denom : 0.f;
  float o[8];
#pragma unroll
  for (int k = 0; k < 8; ++k) {
    float v = acc[k] * inv + b1[lt * 8 + k];
    o[k] = v > 0.f ? v : expm1f(v);
  }
  *(float4*)&outp[(size_t)d * 256 + lt * 8]     = *(float4*)&o[0];
  *(float4*)&outp[(size_t)d * 256 + lt * 8 + 4] = *(float4*)&o[4];
}

// ============================================================
// Fused softmax + aggregation, layer 2 (H=1, C=64).
// v4: one dst per 16-thread group, depth-3 pipeline.
// ============================================================
__global__ __launch_bounds__(256) void agg_l2(
    const int* __restrict__ offs, const int* __restrict__ ssort,
    const float* __restrict__ asrc, const float* __restrict__ adst,
    const unsigned short* __restrict__ h2b, const float* __restrict__ b2,
    float* __restrict__ outp, int n_nodes) {
  const int t = threadIdx.x;
  const int g = t >> 4, lt = t & 15;   // group 0..15, lane 0..15
  const int d = blockIdx.x * 16 + g;
  if (d >= n_nodes) return;
  const int row0 = offs[d], row1 = offs[d + 1];
  const float ad = adst[d];
  float acc[4] = {};
  float denom = 0.f;
  const int m = row1 - row0;

  if (m > 0) {
    const int last = row1 - 1;
    int s0 = ssort[row0];
    int s1 = ssort[min(row0 + 1, last)];
    int s2 = ssort[min(row0 + 2, last)];
    int s3 = ssort[min(row0 + 3, last)];
    float a0 = asrc[s0];
    float a1 = asrc[s1];
    float a2 = asrc[s2];
    bf16x4 p0 = *(const bf16x4*)&h2b[(size_t)s0 * 64 + lt * 4];
    bf16x4 p1 = *(const bf16x4*)&h2b[(size_t)s1 * 64 + lt * 4];
    bf16x4 p2 = *(const bf16x4*)&h2b[(size_t)s2 * 64 + lt * 4];
    for (int j = 0; j < m; ++j) {
      int sN = ssort[min(row0 + j + 4, last)];
      float aN = asrc[s3];
      bf16x4 pN = *(const bf16x4*)&h2b[(size_t)s3 * 64 + lt * 4];
      float sc = a0 + ad;
      sc = sc > 0.f ? sc : 0.2f * sc;
      float ex = __expf(sc);
#pragma unroll
      for (int k = 0; k < 4; ++k) {
        float f = __uint_as_float((unsigned)(unsigned short)p0[k] << 16);
        acc[k] += f * ex;
      }
      denom += ex;
      s3 = sN;
      a0 = a1; a1 = a2; a2 = aN;
      p0 = p1; p1 = p2; p2 = pN;
    }
  }
  float inv = denom > 0.f ? 1.f / denom : 0.f;
  float4 r;
  r.x = acc[0] * inv + b2[lt * 4 + 0];
  r.y = acc[1] * inv + b2[lt * 4 + 1];
  r.z = acc[2] * inv + b2[lt * 4 + 2];
  r.w = acc[3] * inv + b2[lt * 4 + 3];
  *(float4*)&outp[(size_t)d * 64 + lt * 4] = r;
}

// ============================================================
// final MLP head
// ============================================================
__global__ __launch_bounds__(256) void mlp_head(
    const float* __restrict__ emb_in,
    const float* __restrict__ mw1, const float* __restrict__ mb1,
    const float* __restrict__ mw2, const float* __restrict__ mb2,
    float* __restrict__ outp, int n) {
  __shared__ float w1s[64 * 64];
  __shared__ float w2s[64 * 40];
  __shared__ float b1s[64];
  __shared__ float b2s[40];
  int t = threadIdx.x;
  for (int i = t; i < 64 * 64; i += 256) w1s[i] = mw1[i];
  for (int i = t; i < 64 * 40; i += 256) w2s[i] = mw2[i];
  if (t < 64) b1s[t] = mb1[t];
  if (t < 40) b2s[t] = mb2[t];
  __syncthreads();
  int node = blockIdx.x * 256 + t;
  if (node >= n) return;
  float emb[64];
#pragma unroll
  for (int i = 0; i < 64; ++i) emb[i] = emb_in[(size_t)node * 64 + i];
  float hid[64];
#pragma unroll
  for (int j = 0; j < 64; ++j) {
    float s = b1s[j];
#pragma unroll
    for (int i = 0; i < 64; ++i) s += emb[i] * w1s[i * 64 + j];
    hid[j] = s > 0.f ? s : 0.f;
  }
#pragma unroll
  for (int k = 0; k < 40; ++k) {
    float s = b2s[k];
#pragma unroll
    for (int j = 0; j < 64; ++j) s += hid[j] * w2s[j * 40 + k];
    outp[(size_t)node * 40 + k] = s;
  }
}

extern "C" void kernel_launch(void* const* d_in, const int* in_sizes, int n_in,
                              void* d_out, int out_size, void* d_ws, size_t ws_size,
                              hipStream_t stream) {
  const float* x        = (const float*)d_in[0];
  const int*   ei       = (const int*)d_in[1];
  const float* W1       = (const float*)d_in[2];
  const float* att_src1 = (const float*)d_in[3];
  const float* att_dst1 = (const float*)d_in[4];
  const float* b1       = (const float*)d_in[5];
  const float* W2       = (const float*)d_in[6];
  const float* att_src2 = (const float*)d_in[7];
  const float* att_dst2 = (const float*)d_in[8];
  const float* b2       = (const float*)d_in[9];
  const float* mw1      = (const float*)d_in[10];
  const float* mb1      = (const float*)d_in[11];
  const float* mw2      = (const float*)d_in[12];
  const float* mb2      = (const float*)d_in[13];
  float* out = (float*)d_out;

  const int N = N_NODES, E = N_EDGES;
  char* base = (char*)d_ws;
  size_t o = 0;
  auto alloc = [&](size_t n_elems) {   // float-unit (4 B) allocator, 16B-aligned
    void* p = base + o;
    o = (o + n_elems * 4 + 15) & ~(size_t)15;
    return p;
  };
  int* cnt = (int*)alloc(N);
  int* cur = (int*)alloc(N);
  size_t zero_bytes = o;
  int*   offs  = (int*)alloc(N + 2);
  int*   bsum  = (int*)alloc(256);
  int*   bofs  = (int*)alloc(256);
  int*   ssort = (int*)alloc(E);
  float* h1e   = (float*)alloc((size_t)N * 256);
  float* asrc1 = (float*)alloc((size_t)N * 4);
  float* adst1 = (float*)alloc((size_t)N * 4);
  float* emb   = (float*)alloc((size_t)N * 64);
  float* asrc2 = (float*)alloc(N);
  float* adst2 = (float*)alloc(N);
  unsigned short* h1b = (unsigned short*)alloc((size_t)N * 128);  // N*256 bf16
  unsigned short* h2b = (unsigned short*)alloc((size_t)N * 32);   // N*64 bf16
  unsigned short* w1h = (unsigned short*)alloc(512 * 256 / 2);
  unsigned short* w1l = (unsigned short*)alloc(512 * 256 / 2);
  unsigned short* w2h = (unsigned short*)alloc(256 * 64 / 2);
  unsigned short* w2l = (unsigned short*)alloc(256 * 64 / 2);

  hipMemsetAsync(d_ws, 0, zero_bytes, stream);

  const int EB = (E + 255) / 256;

  // ---- build dst-sorted CSR + weight pre-split ----
  hist_k<<<EB, 256, 0, stream>>>(ei, cnt);
  scan1<<<SCAN_B, 256, 0, stream>>>(cnt, offs, bsum);
  scan2<<<1, 256, 0, stream>>>(bsum, bofs);
  scan3<<<SCAN_B, 256, 0, stream>>>(offs, bofs);
  scatter_k<<<EB, 256, 0, stream>>>(ei, offs, cur, ssort);
  wsplit_all<<<(16384 + 2048 + 255) / 256, 256, 0, stream>>>(W1, w1h, w1l,
                                                             W2, w2h, w2l);

  // ---- layer 1 ----
  dim3 g1((N + 127) / 128, 2);
  gemm1_fused<<<g1, 256, 0, stream>>>(x, w1h, w1l, att_src1, att_dst1,
                                      h1b, asrc1, adst1, N);
  agg_l1<<<(N + 7) / 8, 256, 0, stream>>>(offs, ssort, asrc1, adst1, h1b, b1,
                                          h1e, N);

  // ---- layer 2 ----
  dim3 g2((N + 63) / 64, 1);
  gemm2_fused<<<g2, 256, 0, stream>>>(h1e, w2h, w2l, att_src2, att_dst2,
                                      h2b, asrc2, adst2, N);
  agg_l2<<<(N + 15) / 16, 256, 0, stream>>>(offs, ssort, asrc2, adst2, h2b, b2,
                                            emb, N);

  // ---- MLP head ----
  mlp_head<<<(N + 255) / 256, 256, 0, stream>>>(emb, mw1, mb1, mw2, mb2, out, N);
}

// Round 9
// 674.075 us; speedup vs baseline: 1.0002x; 1.0002x over previous
//
#include <hip/hip_runtime.h>

#define N_NODES 50000
#define N_EDGES 800000
#define SCAN_B 196   // ceil(50000/256)

typedef short bf16x8 __attribute__((ext_vector_type(8)));
typedef short bf16x4 __attribute__((ext_vector_type(4)));
typedef float f32x4 __attribute__((ext_vector_type(4)));

#define GLDS16(g, l)                                                  \
  __builtin_amdgcn_global_load_lds(                                   \
      (const __attribute__((address_space(1))) void*)(g),             \
      (__attribute__((address_space(3))) void*)(l), 16, 0, 0)

__device__ __forceinline__ unsigned short f2bf_rne(float x) {
  unsigned u = __float_as_uint(x);
  u += 0x7FFFu + ((u >> 16) & 1u);
  return (unsigned short)(u >> 16);
}

__device__ __forceinline__ void split2(float x, short& hi, short& lo) {
  unsigned u = __float_as_uint(x);
  unsigned short h = (unsigned short)(u >> 16);  // truncate to bf16
  float hf = __uint_as_float((unsigned)h << 16);
  float r = x - hf;
  unsigned short l = (unsigned short)(__float_as_uint(r) >> 16);
  hi = (short)h;
  lo = (short)l;
}

// ============================================================
// Counting sort by dst: hist -> 2-level exclusive scan -> scatter
// ============================================================
__global__ __launch_bounds__(256) void hist_k(const int* __restrict__ ei,
                                              int* __restrict__ cnt) {
  int e = blockIdx.x * 256 + threadIdx.x;
  if (e >= N_EDGES) return;
  atomicAdd(&cnt[ei[N_EDGES + e]], 1);
}

__global__ __launch_bounds__(256) void scan1(const int* __restrict__ cnt,
                                             int* __restrict__ offs,
                                             int* __restrict__ bsum) {
  __shared__ int sh[256];
  int t = threadIdx.x;
  int i = blockIdx.x * 256 + t;
  int v = (i < N_NODES) ? cnt[i] : 0;
  sh[t] = v;
  __syncthreads();
  for (int off = 1; off < 256; off <<= 1) {
    int add = (t >= off) ? sh[t - off] : 0;
    __syncthreads();
    sh[t] += add;
    __syncthreads();
  }
  if (i < N_NODES) offs[i] = sh[t] - v;  // exclusive
  if (t == 255) bsum[blockIdx.x] = sh[255];
}

__global__ __launch_bounds__(256) void scan2(const int* __restrict__ bsum,
                                             int* __restrict__ bofs) {
  __shared__ int sh[256];
  int t = threadIdx.x;
  int v = (t < SCAN_B) ? bsum[t] : 0;
  sh[t] = v;
  __syncthreads();
  for (int off = 1; off < 256; off <<= 1) {
    int add = (t >= off) ? sh[t - off] : 0;
    __syncthreads();
    sh[t] += add;
    __syncthreads();
  }
  if (t < SCAN_B) bofs[t] = sh[t] - v;
}

__global__ __launch_bounds__(256) void scan3(int* __restrict__ offs,
                                             const int* __restrict__ bofs) {
  int i = blockIdx.x * 256 + threadIdx.x;
  if (i < N_NODES) offs[i] += bofs[blockIdx.x];
  if (i == 0) offs[N_NODES] = N_EDGES;
}

__global__ __launch_bounds__(256) void scatter_k(const int* __restrict__ ei,
                                                 const int* __restrict__ offs,
                                                 int* __restrict__ cur,
                                                 int* __restrict__ ssort) {
  int e = blockIdx.x * 256 + threadIdx.x;
  if (e >= N_EDGES) return;
  int d = ei[N_EDGES + e];
  int p = offs[d] + atomicAdd(&cur[d], 1);
  ssort[p] = ei[e];
}

// ============================================================
// Pre-split BOTH weight matrices into bf16 hi/lo, MFMA-fragment
// layout, in one launch. chunk (kq, n)[j] = W[(kq*8+j)*Nn + n]
// W1: 64*256 = 16384 chunks; W2: 32*64 = 2048 chunks.
// ============================================================
__global__ __launch_bounds__(256) void wsplit_all(
    const float* __restrict__ W1, unsigned short* __restrict__ W1h,
    unsigned short* __restrict__ W1l,
    const float* __restrict__ W2, unsigned short* __restrict__ W2h,
    unsigned short* __restrict__ W2l) {
  int i = blockIdx.x * 256 + threadIdx.x;
  const float* W;
  unsigned short *Wh, *Wl;
  int Nn, c;
  if (i < 16384) {
    W = W1; Wh = W1h; Wl = W1l; Nn = 256; c = i;
  } else if (i < 16384 + 2048) {
    W = W2; Wh = W2h; Wl = W2l; Nn = 64; c = i - 16384;
  } else {
    return;
  }
  int kq = c / Nn;
  int n = c % Nn;
  alignas(16) short h[8], l[8];
#pragma unroll
  for (int j = 0; j < 8; ++j) {
    float v = W[(size_t)(kq * 8 + j) * Nn + n];
    split2(v, h[j], l[j]);
  }
  size_t dst = (size_t)c * 8;
  *(bf16x8*)&Wh[dst] = *(bf16x8*)h;
  *(bf16x8*)&Wl[dst] = *(bf16x8*)l;
}

// ============================================================
// GEMM1 fused (round-0 structure): h1b = bf16(x @ W1),
// asrc/adst = att dots. BM=128, BN=128. 4 blocks/CU occupancy is the
// latency-hiding mechanism — do NOT double-buffer (R1 regression).
// ============================================================
__global__ __launch_bounds__(256) void gemm1_fused(
    const float* __restrict__ A,
    const unsigned short* __restrict__ Bh_g, const unsigned short* __restrict__ Bl_g,
    const float* __restrict__ att_s, const float* __restrict__ att_d,
    unsigned short* __restrict__ h1b, float* __restrict__ asrc,
    float* __restrict__ adst, int M) {
  constexpr int K = 512, Nn = 256;
  constexpr int LDA = 40;
  __shared__ short Ah[128][LDA], Al[128][LDA];
  __shared__ short Bh[4 * 128 * 8], Bl[4 * 128 * 8];  // [quad][n_local][8]
  __shared__ float attLds[128][4];

  const int tid = threadIdx.x;
  const int wave = tid >> 6, lane = tid & 63;
  const int quad = lane >> 4, l16 = lane & 15;
  const int wm = (wave >> 1) * 64, wn = (wave & 1) * 64;
  const int rowBase = blockIdx.x * 128;
  const int colBase = blockIdx.y * 128;

  const int ra = tid >> 1, apart = (tid & 1) * 16;
  const int arow = min(rowBase + ra, M - 1);
  const float* aptr = A + (size_t)arow * K + apart;

  f32x4 acc[4][4] = {};

  for (int kc = 0; kc < K / 32; ++kc) {
    // ---- B tile: async global->LDS (4 chunks/thread: 2 hi + 2 lo) ----
#pragma unroll
    for (int inst = 0; inst < 2; ++inst) {
      int seq = inst * 256 + tid;
      int gq = seq >> 7, nl = seq & 127;
      size_t gsrc = (((size_t)kc * 4 + gq) * Nn + colBase + nl) * 8;
      GLDS16(Bh_g + gsrc, &Bh[seq * 8]);
      GLDS16(Bl_g + gsrc, &Bl[seq * 8]);
    }
    // ---- A tile: fp32 load, split, LDS store ----
    {
      alignas(16) short h[16], l[16];
      const float4* a4 = (const float4*)(aptr + kc * 32);
#pragma unroll
      for (int i = 0; i < 4; ++i) {
        float4 v = a4[i];
        split2(v.x, h[i * 4 + 0], l[i * 4 + 0]);
        split2(v.y, h[i * 4 + 1], l[i * 4 + 1]);
        split2(v.z, h[i * 4 + 2], l[i * 4 + 2]);
        split2(v.w, h[i * 4 + 3], l[i * 4 + 3]);
      }
      *(bf16x8*)&Ah[ra][apart]     = ((bf16x8*)h)[0];
      *(bf16x8*)&Ah[ra][apart + 8] = ((bf16x8*)h)[1];
      *(bf16x8*)&Al[ra][apart]     = ((bf16x8*)l)[0];
      *(bf16x8*)&Al[ra][apart + 8] = ((bf16x8*)l)[1];
    }
    __syncthreads();
    // ---- fragments + MFMA ----
    bf16x8 afh[4], afl[4], bfh[4], bfl[4];
#pragma unroll
    for (int mt = 0; mt < 4; ++mt) {
      afh[mt] = *(const bf16x8*)&Ah[wm + mt * 16 + l16][quad * 8];
      afl[mt] = *(const bf16x8*)&Al[wm + mt * 16 + l16][quad * 8];
    }
#pragma unroll
    for (int nt = 0; nt < 4; ++nt) {
      int bi = ((quad << 7) + wn + nt * 16 + l16) * 8;
      bfh[nt] = *(const bf16x8*)&Bh[bi];
      bfl[nt] = *(const bf16x8*)&Bl[bi];
    }
#pragma unroll
    for (int mt = 0; mt < 4; ++mt)
#pragma unroll
      for (int nt = 0; nt < 4; ++nt) {
        acc[mt][nt] = __builtin_amdgcn_mfma_f32_16x16x32_bf16(afh[mt], bfh[nt], acc[mt][nt], 0, 0, 0);
        acc[mt][nt] = __builtin_amdgcn_mfma_f32_16x16x32_bf16(afh[mt], bfl[nt], acc[mt][nt], 0, 0, 0);
        acc[mt][nt] = __builtin_amdgcn_mfma_f32_16x16x32_bf16(afl[mt], bfh[nt], acc[mt][nt], 0, 0, 0);
      }
    __syncthreads();
  }

  // ---- epilogue: bf16 store + fused attention dots ----
  float asw[4], adw[4];
#pragma unroll
  for (int nt = 0; nt < 4; ++nt) {
    int c = colBase + wn + nt * 16 + l16;
    asw[nt] = att_s[c];
    adw[nt] = att_d[c];
  }
#pragma unroll
  for (int mt = 0; mt < 4; ++mt) {
    int rl = wm + mt * 16 + quad * 4;
#pragma unroll
    for (int reg = 0; reg < 4; ++reg) {
      int r = rowBase + rl + reg;
      float s = 0.f, dd = 0.f;
#pragma unroll
      for (int nt = 0; nt < 4; ++nt) {
        float v = acc[mt][nt][reg];
        s += v * asw[nt];
        dd += v * adw[nt];
        if (r < M) {
          int c = colBase + wn + nt * 16 + l16;
          h1b[(size_t)r * Nn + c] = f2bf_rne(v);
        }
      }
#pragma unroll
      for (int off = 1; off < 16; off <<= 1) {
        s += __shfl_xor(s, off);
        dd += __shfl_xor(dd, off);
      }
      if (l16 == 0) {
        attLds[rl + reg][(wn >> 6) * 2 + 0] = s;
        attLds[rl + reg][(wn >> 6) * 2 + 1] = dd;
      }
    }
  }
  __syncthreads();
  if (tid < 128) {
    int r = rowBase + tid;
    if (r < M) {
      int hb = colBase >> 6;  // 0 or 2
      asrc[r * 4 + hb + 0] = attLds[tid][0];
      adst[r * 4 + hb + 0] = attLds[tid][1];
      asrc[r * 4 + hb + 1] = attLds[tid][2];
      adst[r * 4 + hb + 1] = attLds[tid][3];
    }
  }
}

// ============================================================
// GEMM2 fused (round-0 structure, BM=128 — the proven variant).
// ============================================================
__global__ __launch_bounds__(256) void gemm2_fused(
    const float* __restrict__ A,
    const unsigned short* __restrict__ Bh_g, const unsigned short* __restrict__ Bl_g,
    const float* __restrict__ att_s, const float* __restrict__ att_d,
    unsigned short* __restrict__ h2b, float* __restrict__ asrc,
    float* __restrict__ adst, int M) {
  constexpr int K = 256, Nn = 64;
  constexpr int LDA = 40;
  __shared__ short Ah[128][LDA], Al[128][LDA];
  __shared__ short Bh[4 * 64 * 8], Bl[4 * 64 * 8];  // [quad][n][8]
  __shared__ float attLds[128][2];

  const int tid = threadIdx.x;
  const int wave = tid >> 6, lane = tid & 63;
  const int quad = lane >> 4, l16 = lane & 15;
  const int wm = wave * 32;
  const int rowBase = blockIdx.x * 128;

  const int ra = tid >> 1, apart = (tid & 1) * 16;
  const int arow = min(rowBase + ra, M - 1);
  const float* aptr = A + (size_t)arow * K + apart;

  f32x4 acc[2][4] = {};

  for (int kc = 0; kc < K / 32; ++kc) {
    {
      size_t gsrc = (((size_t)kc * 4) * Nn) * 8 + (size_t)tid * 8;
      GLDS16(Bh_g + gsrc, &Bh[tid * 8]);
      GLDS16(Bl_g + gsrc, &Bl[tid * 8]);
    }
    {
      alignas(16) short h[16], l[16];
      const float4* a4 = (const float4*)(aptr + kc * 32);
#pragma unroll
      for (int i = 0; i < 4; ++i) {
        float4 v = a4[i];
        split2(v.x, h[i * 4 + 0], l[i * 4 + 0]);
        split2(v.y, h[i * 4 + 1], l[i * 4 + 1]);
        split2(v.z, h[i * 4 + 2], l[i * 4 + 2]);
        split2(v.w, h[i * 4 + 3], l[i * 4 + 3]);
      }
      *(bf16x8*)&Ah[ra][apart]     = ((bf16x8*)h)[0];
      *(bf16x8*)&Ah[ra][apart + 8] = ((bf16x8*)h)[1];
      *(bf16x8*)&Al[ra][apart]     = ((bf16x8*)l)[0];
      *(bf16x8*)&Al[ra][apart + 8] = ((bf16x8*)l)[1];
    }
    __syncthreads();
    bf16x8 afh[2], afl[2], bfh[4], bfl[4];
#pragma unroll
    for (int mt = 0; mt < 2; ++mt) {
      afh[mt] = *(const bf16x8*)&Ah[wm + mt * 16 + l16][quad * 8];
      afl[mt] = *(const bf16x8*)&Al[wm + mt * 16 + l16][quad * 8];
    }
#pragma unroll
    for (int nt = 0; nt < 4; ++nt) {
      int bi = ((quad << 6) + nt * 16 + l16) * 8;
      bfh[nt] = *(const bf16x8*)&Bh[bi];
      bfl[nt] = *(const bf16x8*)&Bl[bi];
    }
#pragma unroll
    for (int mt = 0; mt < 2; ++mt)
#pragma unroll
      for (int nt = 0; nt < 4; ++nt) {
        acc[mt][nt] = __builtin_amdgcn_mfma_f32_16x16x32_bf16(afh[mt], bfh[nt], acc[mt][nt], 0, 0, 0);
        acc[mt][nt] = __builtin_amdgcn_mfma_f32_16x16x32_bf16(afh[mt], bfl[nt], acc[mt][nt], 0, 0, 0);
        acc[mt][nt] = __builtin_amdgcn_mfma_f32_16x16x32_bf16(afl[mt], bfh[nt], acc[mt][nt], 0, 0, 0);
      }
    __syncthreads();
  }

  float asw[4], adw[4];
#pragma unroll
  for (int nt = 0; nt < 4; ++nt) {
    int c = nt * 16 + l16;
    asw[nt] = att_s[c];
    adw[nt] = att_d[c];
  }
#pragma unroll
  for (int mt = 0; mt < 2; ++mt) {
    int rl = wm + mt * 16 + quad * 4;
#pragma unroll
    for (int reg = 0; reg < 4; ++reg) {
      int r = rowBase + rl + reg;
      float s = 0.f, dd = 0.f;
#pragma unroll
      for (int nt = 0; nt < 4; ++nt) {
        float v = acc[mt][nt][reg];
        s += v * asw[nt];
        dd += v * adw[nt];
        if (r < M) {
          int c = nt * 16 + l16;
          h2b[(size_t)r * Nn + c] = f2bf_rne(v);
        }
      }
#pragma unroll
      for (int off = 1; off < 16; off <<= 1) {
        s += __shfl_xor(s, off);
        dd += __shfl_xor(dd, off);
      }
      if (l16 == 0) {
        attLds[rl + reg][0] = s;
        attLds[rl + reg][1] = dd;
      }
    }
  }
  __syncthreads();
  if (tid < 128) {
    int r = rowBase + tid;
    if (r < M) {
      asrc[r] = attLds[tid][0];
      adst[r] = attLds[tid][1];
    }
  }
}

// ============================================================
// Fused softmax + aggregation, layer 1 (H=4, C=64).
// v4: one dst per 32-thread group, zero LDS/barriers, depth-3 reg
// pipeline. 91 µs — at the random-512B-gather fabric ceiling
// (R5/R6: three pipeline schedules all converge here).
// ============================================================
__global__ __launch_bounds__(256) void agg_l1(
    const int* __restrict__ offs, const int* __restrict__ ssort,
    const float* __restrict__ asrc, const float* __restrict__ adst,
    const unsigned short* __restrict__ h1b, const float* __restrict__ b1,
    float* __restrict__ outp, int n_nodes) {
  const int t = threadIdx.x;
  const int g = t >> 5, lt = t & 31;   // group 0..7, lane-in-group 0..31
  const int d = blockIdx.x * 8 + g;
  if (d >= n_nodes) return;
  const int h = lt >> 3;               // head of this lane's 8 features
  const int row0 = offs[d], row1 = offs[d + 1];
  const float ad = adst[d * 4 + h];
  float acc[8] = {};
  float denom = 0.f;
  const int m = row1 - row0;

  if (m > 0) {
    const int last = row1 - 1;
    // ---- prologue: 3 rows in flight ----
    int s0 = ssort[row0];
    int s1 = ssort[min(row0 + 1, last)];
    int s2 = ssort[min(row0 + 2, last)];
    int s3 = ssort[min(row0 + 3, last)];
    float a0 = asrc[s0 * 4 + h];
    float a1 = asrc[s1 * 4 + h];
    float a2 = asrc[s2 * 4 + h];
    bf16x8 p0 = *(const bf16x8*)&h1b[(size_t)s0 * 256 + lt * 8];
    bf16x8 p1 = *(const bf16x8*)&h1b[(size_t)s1 * 256 + lt * 8];
    bf16x8 p2 = *(const bf16x8*)&h1b[(size_t)s2 * 256 + lt * 8];
    for (int j = 0; j < m; ++j) {
      // ---- issue loads for j+3 (clamped; tail re-reads last row) ----
      int sN = ssort[min(row0 + j + 4, last)];
      float aN = asrc[s3 * 4 + h];
      bf16x8 pN = *(const bf16x8*)&h1b[(size_t)s3 * 256 + lt * 8];
      // ---- compute edge j ----
      float sc = a0 + ad;
      sc = sc > 0.f ? sc : 0.2f * sc;
      float ex = __expf(sc);
#pragma unroll
      for (int k = 0; k < 8; ++k) {
        float f = __uint_as_float((unsigned)(unsigned short)p0[k] << 16);
        acc[k] += f * ex;
      }
      denom += ex;
      // ---- rotate (static names only) ----
      s3 = sN;
      a0 = a1; a1 = a2; a2 = aN;
      p0 = p1; p1 = p2; p2 = pN;
    }
  }
  float inv = denom > 0.f ? 1.f / denom : 0.f;
  float o[8];
#pragma unroll
  for (int k = 0; k < 8; ++k) {
    float v = acc[k] * inv + b1[lt * 8 + k];
    o[k] = v > 0.f ? v : expm1f(v);
  }
  *(float4*)&outp[(size_t)d * 256 + lt * 8]     = *(float4*)&o[0];
  *(float4*)&outp[(size_t)d * 256 + lt * 8 + 4] = *(float4*)&o[4];
}

// ============================================================
// Fused softmax + aggregation, layer 2 (H=1, C=64).
// v4: one dst per 16-thread group, depth-3 pipeline.
// ============================================================
__global__ __launch_bounds__(256) void agg_l2(
    const int* __restrict__ offs, const int* __restrict__ ssort,
    const float* __restrict__ asrc, const float* __restrict__ adst,
    const unsigned short* __restrict__ h2b, const float* __restrict__ b2,
    float* __restrict__ outp, int n_nodes) {
  const int t = threadIdx.x;
  const int g = t >> 4, lt = t & 15;   // group 0..15, lane 0..15
  const int d = blockIdx.x * 16 + g;
  if (d >= n_nodes) return;
  const int row0 = offs[d], row1 = offs[d + 1];
  const float ad = adst[d];
  float acc[4] = {};
  float denom = 0.f;
  const int m = row1 - row0;

  if (m > 0) {
    const int last = row1 - 1;
    int s0 = ssort[row0];
    int s1 = ssort[min(row0 + 1, last)];
    int s2 = ssort[min(row0 + 2, last)];
    int s3 = ssort[min(row0 + 3, last)];
    float a0 = asrc[s0];
    float a1 = asrc[s1];
    float a2 = asrc[s2];
    bf16x4 p0 = *(const bf16x4*)&h2b[(size_t)s0 * 64 + lt * 4];
    bf16x4 p1 = *(const bf16x4*)&h2b[(size_t)s1 * 64 + lt * 4];
    bf16x4 p2 = *(const bf16x4*)&h2b[(size_t)s2 * 64 + lt * 4];
    for (int j = 0; j < m; ++j) {
      int sN = ssort[min(row0 + j + 4, last)];
      float aN = asrc[s3];
      bf16x4 pN = *(const bf16x4*)&h2b[(size_t)s3 * 64 + lt * 4];
      float sc = a0 + ad;
      sc = sc > 0.f ? sc : 0.2f * sc;
      float ex = __expf(sc);
#pragma unroll
      for (int k = 0; k < 4; ++k) {
        float f = __uint_as_float((unsigned)(unsigned short)p0[k] << 16);
        acc[k] += f * ex;
      }
      denom += ex;
      s3 = sN;
      a0 = a1; a1 = a2; a2 = aN;
      p0 = p1; p1 = p2; p2 = pN;
    }
  }
  float inv = denom > 0.f ? 1.f / denom : 0.f;
  float4 r;
  r.x = acc[0] * inv + b2[lt * 4 + 0];
  r.y = acc[1] * inv + b2[lt * 4 + 1];
  r.z = acc[2] * inv + b2[lt * 4 + 2];
  r.w = acc[3] * inv + b2[lt * 4 + 3];
  *(float4*)&outp[(size_t)d * 64 + lt * 4] = r;
}

// ============================================================
// final MLP head (v1, proven)
// ============================================================
__global__ __launch_bounds__(256) void mlp_head(
    const float* __restrict__ emb_in,
    const float* __restrict__ mw1, const float* __restrict__ mb1,
    const float* __restrict__ mw2, const float* __restrict__ mb2,
    float* __restrict__ outp, int n) {
  __shared__ float w1s[64 * 64];
  __shared__ float w2s[64 * 40];
  __shared__ float b1s[64];
  __shared__ float b2s[40];
  int t = threadIdx.x;
  for (int i = t; i < 64 * 64; i += 256) w1s[i] = mw1[i];
  for (int i = t; i < 64 * 40; i += 256) w2s[i] = mw2[i];
  if (t < 64) b1s[t] = mb1[t];
  if (t < 40) b2s[t] = mb2[t];
  __syncthreads();
  int node = blockIdx.x * 256 + t;
  if (node >= n) return;
  float emb[64];
#pragma unroll
  for (int i = 0; i < 64; ++i) emb[i] = emb_in[(size_t)node * 64 + i];
  float hid[64];
#pragma unroll
  for (int j = 0; j < 64; ++j) {
    float s = b1s[j];
#pragma unroll
    for (int i = 0; i < 64; ++i) s += emb[i] * w1s[i * 64 + j];
    hid[j] = s > 0.f ? s : 0.f;
  }
#pragma unroll
  for (int k = 0; k < 40; ++k) {
    float s = b2s[k];
#pragma unroll
    for (int j = 0; j < 64; ++j) s += hid[j] * w2s[j * 40 + k];
    outp[(size_t)node * 40 + k] = s;
  }
}

extern "C" void kernel_launch(void* const* d_in, const int* in_sizes, int n_in,
                              void* d_out, int out_size, void* d_ws, size_t ws_size,
                              hipStream_t stream) {
  const float* x        = (const float*)d_in[0];
  const int*   ei       = (const int*)d_in[1];
  const float* W1       = (const float*)d_in[2];
  const float* att_src1 = (const float*)d_in[3];
  const float* att_dst1 = (const float*)d_in[4];
  const float* b1       = (const float*)d_in[5];
  const float* W2       = (const float*)d_in[6];
  const float* att_src2 = (const float*)d_in[7];
  const float* att_dst2 = (const float*)d_in[8];
  const float* b2       = (const float*)d_in[9];
  const float* mw1      = (const float*)d_in[10];
  const float* mb1      = (const float*)d_in[11];
  const float* mw2      = (const float*)d_in[12];
  const float* mb2      = (const float*)d_in[13];
  float* out = (float*)d_out;

  const int N = N_NODES, E = N_EDGES;
  char* base = (char*)d_ws;
  size_t o = 0;
  auto alloc = [&](size_t n_elems) {   // float-unit (4 B) allocator, 16B-aligned
    void* p = base + o;
    o = (o + n_elems * 4 + 15) & ~(size_t)15;
    return p;
  };
  int* cnt = (int*)alloc(N);
  int* cur = (int*)alloc(N);
  size_t zero_bytes = o;
  int*   offs  = (int*)alloc(N + 2);
  int*   bsum  = (int*)alloc(256);
  int*   bofs  = (int*)alloc(256);
  int*   ssort = (int*)alloc(E);
  float* h1e   = (float*)alloc((size_t)N * 256);
  float* asrc1 = (float*)alloc((size_t)N * 4);
  float* adst1 = (float*)alloc((size_t)N * 4);
  float* emb   = (float*)alloc((size_t)N * 64);
  float* asrc2 = (float*)alloc(N);
  float* adst2 = (float*)alloc(N);
  unsigned short* h1b = (unsigned short*)alloc((size_t)N * 128);  // N*256 bf16
  unsigned short* h2b = (unsigned short*)alloc((size_t)N * 32);   // N*64 bf16
  unsigned short* w1h = (unsigned short*)alloc(512 * 256 / 2);
  unsigned short* w1l = (unsigned short*)alloc(512 * 256 / 2);
  unsigned short* w2h = (unsigned short*)alloc(256 * 64 / 2);
  unsigned short* w2l = (unsigned short*)alloc(256 * 64 / 2);

  hipMemsetAsync(d_ws, 0, zero_bytes, stream);

  const int EB = (E + 255) / 256;

  // ---- build dst-sorted CSR + weight pre-split ----
  hist_k<<<EB, 256, 0, stream>>>(ei, cnt);
  scan1<<<SCAN_B, 256, 0, stream>>>(cnt, offs, bsum);
  scan2<<<1, 256, 0, stream>>>(bsum, bofs);
  scan3<<<SCAN_B, 256, 0, stream>>>(offs, bofs);
  scatter_k<<<EB, 256, 0, stream>>>(ei, offs, cur, ssort);
  wsplit_all<<<(16384 + 2048 + 255) / 256, 256, 0, stream>>>(W1, w1h, w1l,
                                                             W2, w2h, w2l);

  // ---- layer 1 ----
  dim3 g1((N + 127) / 128, 2);
  gemm1_fused<<<g1, 256, 0, stream>>>(x, w1h, w1l, att_src1, att_dst1,
                                      h1b, asrc1, adst1, N);
  agg_l1<<<(N + 7) / 8, 256, 0, stream>>>(offs, ssort, asrc1, adst1, h1b, b1,
                                          h1e, N);

  // ---- layer 2 ----
  dim3 g2((N + 127) / 128, 1);
  gemm2_fused<<<g2, 256, 0, stream>>>(h1e, w2h, w2l, att_src2, att_dst2,
                                      h2b, asrc2, adst2, N);
  agg_l2<<<(N + 15) / 16, 256, 0, stream>>>(offs, ssort, asrc2, adst2, h2b, b2,
                                            emb, N);

  // ---- MLP head ----
  mlp_head<<<(N + 255) / 256, 256, 0, stream>>>(emb, mw1, mb1, mw2, mb2, out, N);
}

// Round 11
// 465.650 us; speedup vs baseline: 1.4479x; 1.4476x over previous
//
#include <hip/hip_runtime.h>

#define N_NODES 50000
#define N_EDGES 800000
#define SCAN_B 196   // ceil(50000/256)

typedef short bf16x8 __attribute__((ext_vector_type(8)));
typedef short bf16x4 __attribute__((ext_vector_type(4)));
typedef float f32x4 __attribute__((ext_vector_type(4)));

#define GLDS16(g, l)                                                  \
  __builtin_amdgcn_global_load_lds(                                   \
      (const __attribute__((address_space(1))) void*)(g),             \
      (__attribute__((address_space(3))) void*)(l), 16, 0, 0)

__device__ __forceinline__ unsigned short f2bf_rne(float x) {
  unsigned u = __float_as_uint(x);
  u += 0x7FFFu + ((u >> 16) & 1u);
  return (unsigned short)(u >> 16);
}

__device__ __forceinline__ void split2(float x, short& hi, short& lo) {
  unsigned u = __float_as_uint(x);
  unsigned short h = (unsigned short)(u >> 16);  // truncate to bf16
  float hf = __uint_as_float((unsigned)h << 16);
  float r = x - hf;
  unsigned short l = (unsigned short)(__float_as_uint(r) >> 16);
  hi = (short)h;
  lo = (short)l;
}

// ============================================================
// Counting sort by dst: hist -> 2-level exclusive scan -> scatter
// ============================================================
__global__ __launch_bounds__(256) void hist_k(const int* __restrict__ ei,
                                              int* __restrict__ cnt) {
  int e = blockIdx.x * 256 + threadIdx.x;
  if (e >= N_EDGES) return;
  atomicAdd(&cnt[ei[N_EDGES + e]], 1);
}

__global__ __launch_bounds__(256) void scan1(const int* __restrict__ cnt,
                                             int* __restrict__ offs,
                                             int* __restrict__ bsum) {
  __shared__ int sh[256];
  int t = threadIdx.x;
  int i = blockIdx.x * 256 + t;
  int v = (i < N_NODES) ? cnt[i] : 0;
  sh[t] = v;
  __syncthreads();
  for (int off = 1; off < 256; off <<= 1) {
    int add = (t >= off) ? sh[t - off] : 0;
    __syncthreads();
    sh[t] += add;
    __syncthreads();
  }
  if (i < N_NODES) offs[i] = sh[t] - v;  // exclusive
  if (t == 255) bsum[blockIdx.x] = sh[255];
}

__global__ __launch_bounds__(256) void scan2(const int* __restrict__ bsum,
                                             int* __restrict__ bofs) {
  __shared__ int sh[256];
  int t = threadIdx.x;
  int v = (t < SCAN_B) ? bsum[t] : 0;
  sh[t] = v;
  __syncthreads();
  for (int off = 1; off < 256; off <<= 1) {
    int add = (t >= off) ? sh[t - off] : 0;
    __syncthreads();
    sh[t] += add;
    __syncthreads();
  }
  if (t < SCAN_B) bofs[t] = sh[t] - v;
}

__global__ __launch_bounds__(256) void scan3(int* __restrict__ offs,
                                             const int* __restrict__ bofs) {
  int i = blockIdx.x * 256 + threadIdx.x;
  if (i < N_NODES) offs[i] += bofs[blockIdx.x];
  if (i == 0) offs[N_NODES] = N_EDGES;
}

__global__ __launch_bounds__(256) void scatter_k(const int* __restrict__ ei,
                                                 const int* __restrict__ offs,
                                                 int* __restrict__ cur,
                                                 int* __restrict__ ssort) {
  int e = blockIdx.x * 256 + threadIdx.x;
  if (e >= N_EDGES) return;
  int d = ei[N_EDGES + e];
  int p = offs[d] + atomicAdd(&cur[d], 1);
  ssort[p] = ei[e];
}

// ============================================================
// Pre-split BOTH weight matrices into bf16 hi/lo, MFMA-fragment
// layout, in one launch. chunk (kq, n)[j] = W[(kq*8+j)*Nn + n]
// W1: 64*256 = 16384 chunks; W2: 32*64 = 2048 chunks.
// ============================================================
__global__ __launch_bounds__(256) void wsplit_all(
    const float* __restrict__ W1, unsigned short* __restrict__ W1h,
    unsigned short* __restrict__ W1l,
    const float* __restrict__ W2, unsigned short* __restrict__ W2h,
    unsigned short* __restrict__ W2l) {
  int i = blockIdx.x * 256 + threadIdx.x;
  const float* W;
  unsigned short *Wh, *Wl;
  int Nn, c;
  if (i < 16384) {
    W = W1; Wh = W1h; Wl = W1l; Nn = 256; c = i;
  } else if (i < 16384 + 2048) {
    W = W2; Wh = W2h; Wl = W2l; Nn = 64; c = i - 16384;
  } else {
    return;
  }
  int kq = c / Nn;
  int n = c % Nn;
  alignas(16) short h[8], l[8];
#pragma unroll
  for (int j = 0; j < 8; ++j) {
    float v = W[(size_t)(kq * 8 + j) * Nn + n];
    split2(v, h[j], l[j]);
  }
  size_t dst = (size_t)c * 8;
  *(bf16x8*)&Wh[dst] = *(bf16x8*)h;
  *(bf16x8*)&Wl[dst] = *(bf16x8*)l;
}

// ============================================================
// GEMM1 fused (round-0 structure): h1b = bf16(x @ W1),
// asrc/adst = att dots. BM=128, BN=128. 4 blocks/CU occupancy is the
// latency-hiding mechanism — do NOT double-buffer (R1 regression).
// ============================================================
__global__ __launch_bounds__(256) void gemm1_fused(
    const float* __restrict__ A,
    const unsigned short* __restrict__ Bh_g, const unsigned short* __restrict__ Bl_g,
    const float* __restrict__ att_s, const float* __restrict__ att_d,
    unsigned short* __restrict__ h1b, float* __restrict__ asrc,
    float* __restrict__ adst, int M) {
  constexpr int K = 512, Nn = 256;
  constexpr int LDA = 40;
  __shared__ short Ah[128][LDA], Al[128][LDA];
  __shared__ short Bh[4 * 128 * 8], Bl[4 * 128 * 8];  // [quad][n_local][8]
  __shared__ float attLds[128][4];

  const int tid = threadIdx.x;
  const int wave = tid >> 6, lane = tid & 63;
  const int quad = lane >> 4, l16 = lane & 15;
  const int wm = (wave >> 1) * 64, wn = (wave & 1) * 64;
  const int rowBase = blockIdx.x * 128;
  const int colBase = blockIdx.y * 128;

  const int ra = tid >> 1, apart = (tid & 1) * 16;
  const int arow = min(rowBase + ra, M - 1);
  const float* aptr = A + (size_t)arow * K + apart;

  f32x4 acc[4][4] = {};

  for (int kc = 0; kc < K / 32; ++kc) {
    // ---- B tile: async global->LDS (4 chunks/thread: 2 hi + 2 lo) ----
#pragma unroll
    for (int inst = 0; inst < 2; ++inst) {
      int seq = inst * 256 + tid;
      int gq = seq >> 7, nl = seq & 127;
      size_t gsrc = (((size_t)kc * 4 + gq) * Nn + colBase + nl) * 8;
      GLDS16(Bh_g + gsrc, &Bh[seq * 8]);
      GLDS16(Bl_g + gsrc, &Bl[seq * 8]);
    }
    // ---- A tile: fp32 load, split, LDS store ----
    {
      alignas(16) short h[16], l[16];
      const float4* a4 = (const float4*)(aptr + kc * 32);
#pragma unroll
      for (int i = 0; i < 4; ++i) {
        float4 v = a4[i];
        split2(v.x, h[i * 4 + 0], l[i * 4 + 0]);
        split2(v.y, h[i * 4 + 1], l[i * 4 + 1]);
        split2(v.z, h[i * 4 + 2], l[i * 4 + 2]);
        split2(v.w, h[i * 4 + 3], l[i * 4 + 3]);
      }
      *(bf16x8*)&Ah[ra][apart]     = ((bf16x8*)h)[0];
      *(bf16x8*)&Ah[ra][apart + 8] = ((bf16x8*)h)[1];
      *(bf16x8*)&Al[ra][apart]     = ((bf16x8*)l)[0];
      *(bf16x8*)&Al[ra][apart + 8] = ((bf16x8*)l)[1];
    }
    __syncthreads();
    // ---- fragments + MFMA ----
    bf16x8 afh[4], afl[4], bfh[4], bfl[4];
#pragma unroll
    for (int mt = 0; mt < 4; ++mt) {
      afh[mt] = *(const bf16x8*)&Ah[wm + mt * 16 + l16][quad * 8];
      afl[mt] = *(const bf16x8*)&Al[wm + mt * 16 + l16][quad * 8];
    }
#pragma unroll
    for (int nt = 0; nt < 4; ++nt) {
      int bi = ((quad << 7) + wn + nt * 16 + l16) * 8;
      bfh[nt] = *(const bf16x8*)&Bh[bi];
      bfl[nt] = *(const bf16x8*)&Bl[bi];
    }
#pragma unroll
    for (int mt = 0; mt < 4; ++mt)
#pragma unroll
      for (int nt = 0; nt < 4; ++nt) {
        acc[mt][nt] = __builtin_amdgcn_mfma_f32_16x16x32_bf16(afh[mt], bfh[nt], acc[mt][nt], 0, 0, 0);
        acc[mt][nt] = __builtin_amdgcn_mfma_f32_16x16x32_bf16(afh[mt], bfl[nt], acc[mt][nt], 0, 0, 0);
        acc[mt][nt] = __builtin_amdgcn_mfma_f32_16x16x32_bf16(afl[mt], bfh[nt], acc[mt][nt], 0, 0, 0);
      }
    __syncthreads();
  }

  // ---- epilogue: bf16 store + fused attention dots ----
  float asw[4], adw[4];
#pragma unroll
  for (int nt = 0; nt < 4; ++nt) {
    int c = colBase + wn + nt * 16 + l16;
    asw[nt] = att_s[c];
    adw[nt] = att_d[c];
  }
#pragma unroll
  for (int mt = 0; mt < 4; ++mt) {
    int rl = wm + mt * 16 + quad * 4;
#pragma unroll
    for (int reg = 0; reg < 4; ++reg) {
      int r = rowBase + rl + reg;
      float s = 0.f, dd = 0.f;
#pragma unroll
      for (int nt = 0; nt < 4; ++nt) {
        float v = acc[mt][nt][reg];
        s += v * asw[nt];
        dd += v * adw[nt];
        if (r < M) {
          int c = colBase + wn + nt * 16 + l16;
          h1b[(size_t)r * Nn + c] = f2bf_rne(v);
        }
      }
#pragma unroll
      for (int off = 1; off < 16; off <<= 1) {
        s += __shfl_xor(s, off);
        dd += __shfl_xor(dd, off);
      }
      if (l16 == 0) {
        attLds[rl + reg][(wn >> 6) * 2 + 0] = s;
        attLds[rl + reg][(wn >> 6) * 2 + 1] = dd;
      }
    }
  }
  __syncthreads();
  if (tid < 128) {
    int r = rowBase + tid;
    if (r < M) {
      int hb = colBase >> 6;  // 0 or 2
      asrc[r * 4 + hb + 0] = attLds[tid][0];
      adst[r * 4 + hb + 0] = attLds[tid][1];
      asrc[r * 4 + hb + 1] = attLds[tid][2];
      adst[r * 4 + hb + 1] = attLds[tid][3];
    }
  }
}

// ============================================================
// GEMM2 fused (round-0 structure, BM=128 — the proven variant).
// ============================================================
__global__ __launch_bounds__(256) void gemm2_fused(
    const float* __restrict__ A,
    const unsigned short* __restrict__ Bh_g, const unsigned short* __restrict__ Bl_g,
    const float* __restrict__ att_s, const float* __restrict__ att_d,
    unsigned short* __restrict__ h2b, float* __restrict__ asrc,
    float* __restrict__ adst, int M) {
  constexpr int K = 256, Nn = 64;
  constexpr int LDA = 40;
  __shared__ short Ah[128][LDA], Al[128][LDA];
  __shared__ short Bh[4 * 64 * 8], Bl[4 * 64 * 8];  // [quad][n][8]
  __shared__ float attLds[128][2];

  const int tid = threadIdx.x;
  const int wave = tid >> 6, lane = tid & 63;
  const int quad = lane >> 4, l16 = lane & 15;
  const int wm = wave * 32;
  const int rowBase = blockIdx.x * 128;

  const int ra = tid >> 1, apart = (tid & 1) * 16;
  const int arow = min(rowBase + ra, M - 1);
  const float* aptr = A + (size_t)arow * K + apart;

  f32x4 acc[2][4] = {};

  for (int kc = 0; kc < K / 32; ++kc) {
    {
      size_t gsrc = (((size_t)kc * 4) * Nn) * 8 + (size_t)tid * 8;
      GLDS16(Bh_g + gsrc, &Bh[tid * 8]);
      GLDS16(Bl_g + gsrc, &Bl[tid * 8]);
    }
    {
      alignas(16) short h[16], l[16];
      const float4* a4 = (const float4*)(aptr + kc * 32);
#pragma unroll
      for (int i = 0; i < 4; ++i) {
        float4 v = a4[i];
        split2(v.x, h[i * 4 + 0], l[i * 4 + 0]);
        split2(v.y, h[i * 4 + 1], l[i * 4 + 1]);
        split2(v.z, h[i * 4 + 2], l[i * 4 + 2]);
        split2(v.w, h[i * 4 + 3], l[i * 4 + 3]);
      }
      *(bf16x8*)&Ah[ra][apart]     = ((bf16x8*)h)[0];
      *(bf16x8*)&Ah[ra][apart + 8] = ((bf16x8*)h)[1];
      *(bf16x8*)&Al[ra][apart]     = ((bf16x8*)l)[0];
      *(bf16x8*)&Al[ra][apart + 8] = ((bf16x8*)l)[1];
    }
    __syncthreads();
    bf16x8 afh[2], afl[2], bfh[4], bfl[4];
#pragma unroll
    for (int mt = 0; mt < 2; ++mt) {
      afh[mt] = *(const bf16x8*)&Ah[wm + mt * 16 + l16][quad * 8];
      afl[mt] = *(const bf16x8*)&Al[wm + mt * 16 + l16][quad * 8];
    }
#pragma unroll
    for (int nt = 0; nt < 4; ++nt) {
      int bi = ((quad << 6) + nt * 16 + l16) * 8;
      bfh[nt] = *(const bf16x8*)&Bh[bi];
      bfl[nt] = *(const bf16x8*)&Bl[bi];
    }
#pragma unroll
    for (int mt = 0; mt < 2; ++mt)
#pragma unroll
      for (int nt = 0; nt < 4; ++nt) {
        acc[mt][nt] = __builtin_amdgcn_mfma_f32_16x16x32_bf16(afh[mt], bfh[nt], acc[mt][nt], 0, 0, 0);
        acc[mt][nt] = __builtin_amdgcn_mfma_f32_16x16x32_bf16(afh[mt], bfl[nt], acc[mt][nt], 0, 0, 0);
        acc[mt][nt] = __builtin_amdgcn_mfma_f32_16x16x32_bf16(afl[mt], bfh[nt], acc[mt][nt], 0, 0, 0);
      }
    __syncthreads();
  }

  float asw[4], adw[4];
#pragma unroll
  for (int nt = 0; nt < 4; ++nt) {
    int c = nt * 16 + l16;
    asw[nt] = att_s[c];
    adw[nt] = att_d[c];
  }
#pragma unroll
  for (int mt = 0; mt < 2; ++mt) {
    int rl = wm + mt * 16 + quad * 4;
#pragma unroll
    for (int reg = 0; reg < 4; ++reg) {
      int r = rowBase + rl + reg;
      float s = 0.f, dd = 0.f;
#pragma unroll
      for (int nt = 0; nt < 4; ++nt) {
        float v = acc[mt][nt][reg];
        s += v * asw[nt];
        dd += v * adw[nt];
        if (r < M) {
          int c = nt * 16 + l16;
          h2b[(size_t)r * Nn + c] = f2bf_rne(v);
        }
      }
#pragma unroll
      for (int off = 1; off < 16; off <<= 1) {
        s += __shfl_xor(s, off);
        dd += __shfl_xor(dd, off);
      }
      if (l16 == 0) {
        attLds[rl + reg][0] = s;
        attLds[rl + reg][1] = dd;
      }
    }
  }
  __syncthreads();
  if (tid < 128) {
    int r = rowBase + tid;
    if (r < M) {
      asrc[r] = attLds[tid][0];
      adst[r] = attLds[tid][1];
    }
  }
}

// ============================================================
// Fused softmax + aggregation, layer 1 (H=4, C=64).
// v4: one dst per 32-thread group, zero LDS/barriers, depth-3 reg
// pipeline. 91 µs — at the random-512B-gather fabric ceiling
// (R5/R6: three pipeline schedules all converge here).
// ============================================================
__global__ __launch_bounds__(256) void agg_l1(
    const int* __restrict__ offs, const int* __restrict__ ssort,
    const float* __restrict__ asrc, const float* __restrict__ adst,
    const unsigned short* __restrict__ h1b, const float* __restrict__ b1,
    float* __restrict__ outp, int n_nodes) {
  const int t = threadIdx.x;
  const int g = t >> 5, lt = t & 31;   // group 0..7, lane-in-group 0..31
  const int d = blockIdx.x * 8 + g;
  if (d >= n_nodes) return;
  const int h = lt >> 3;               // head of this lane's 8 features
  const int row0 = offs[d], row1 = offs[d + 1];
  const float ad = adst[d * 4 + h];
  float acc[8] = {};
  float denom = 0.f;
  const int m = row1 - row0;

  if (m > 0) {
    const int last = row1 - 1;
    // ---- prologue: 3 rows in flight ----
    int s0 = ssort[row0];
    int s1 = ssort[min(row0 + 1, last)];
    int s2 = ssort[min(row0 + 2, last)];
    int s3 = ssort[min(row0 + 3, last)];
    float a0 = asrc[s0 * 4 + h];
    float a1 = asrc[s1 * 4 + h];
    float a2 = asrc[s2 * 4 + h];
    bf16x8 p0 = *(const bf16x8*)&h1b[(size_t)s0 * 256 + lt * 8];
    bf16x8 p1 = *(const bf16x8*)&h1b[(size_t)s1 * 256 + lt * 8];
    bf16x8 p2 = *(const bf16x8*)&h1b[(size_t)s2 * 256 + lt * 8];
    for (int j = 0; j < m; ++j) {
      // ---- issue loads for j+3 (clamped; tail re-reads last row) ----
      int sN = ssort[min(row0 + j + 4, last)];
      float aN = asrc[s3 * 4 + h];
      bf16x8 pN = *(const bf16x8*)&h1b[(size_t)s3 * 256 + lt * 8];
      // ---- compute edge j ----
      float sc = a0 + ad;
      sc = sc > 0.f ? sc : 0.2f * sc;
      float ex = __expf(sc);
#pragma unroll
      for (int k = 0; k < 8; ++k) {
        float f = __uint_as_float((unsigned)(unsigned short)p0[k] << 16);
        acc[k] += f * ex;
      }
      denom += ex;
      // ---- rotate (static names only) ----
      s3 = sN;
      a0 = a1; a1 = a2; a2 = aN;
      p0 = p1; p1 = p2; p2 = pN;
    }
  }
  float inv = denom > 0.f ? 1.f / denom : 0.f;
  float o[8];
#pragma unroll
  for (int k = 0; k < 8; ++k) {
    float v = acc[k] * inv + b1[lt * 8 + k];
    o[k] = v > 0.f ? v : expm1f(v);
  }
  *(float4*)&outp[(size_t)d * 256 + lt * 8]     = *(float4*)&o[0];
  *(float4*)&outp[(size_t)d * 256 + lt * 8 + 4] = *(float4*)&o[4];
}

// ============================================================
// Fused softmax + aggregation, layer 2 (H=1, C=64).
// v4: one dst per 16-thread group, depth-3 pipeline.
// ============================================================
__global__ __launch_bounds__(256) void agg_l2(
    const int* __restrict__ offs, const int* __restrict__ ssort,
    const float* __restrict__ asrc, const float* __restrict__ adst,
    const unsigned short* __restrict__ h2b, const float* __restrict__ b2,
    float* __restrict__ outp, int n_nodes) {
  const int t = threadIdx.x;
  const int g = t >> 4, lt = t & 15;   // group 0..15, lane 0..15
  const int d = blockIdx.x * 16 + g;
  if (d >= n_nodes) return;
  const int row0 = offs[d], row1 = offs[d + 1];
  const float ad = adst[d];
  float acc[4] = {};
  float denom = 0.f;
  const int m = row1 - row0;

  if (m > 0) {
    const int last = row1 - 1;
    int s0 = ssort[row0];
    int s1 = ssort[min(row0 + 1, last)];
    int s2 = ssort[min(row0 + 2, last)];
    int s3 = ssort[min(row0 + 3, last)];
    float a0 = asrc[s0];
    float a1 = asrc[s1];
    float a2 = asrc[s2];
    bf16x4 p0 = *(const bf16x4*)&h2b[(size_t)s0 * 64 + lt * 4];
    bf16x4 p1 = *(const bf16x4*)&h2b[(size_t)s1 * 64 + lt * 4];
    bf16x4 p2 = *(const bf16x4*)&h2b[(size_t)s2 * 64 + lt * 4];
    for (int j = 0; j < m; ++j) {
      int sN = ssort[min(row0 + j + 4, last)];
      float aN = asrc[s3];
      bf16x4 pN = *(const bf16x4*)&h2b[(size_t)s3 * 64 + lt * 4];
      float sc = a0 + ad;
      sc = sc > 0.f ? sc : 0.2f * sc;
      float ex = __expf(sc);
#pragma unroll
      for (int k = 0; k < 4; ++k) {
        float f = __uint_as_float((unsigned)(unsigned short)p0[k] << 16);
        acc[k] += f * ex;
      }
      denom += ex;
      s3 = sN;
      a0 = a1; a1 = a2; a2 = aN;
      p0 = p1; p1 = p2; p2 = pN;
    }
  }
  float inv = denom > 0.f ? 1.f / denom : 0.f;
  float4 r;
  r.x = acc[0] * inv + b2[lt * 4 + 0];
  r.y = acc[1] * inv + b2[lt * 4 + 1];
  r.z = acc[2] * inv + b2[lt * 4 + 2];
  r.w = acc[3] * inv + b2[lt * 4 + 3];
  *(float4*)&outp[(size_t)d * 64 + lt * 4] = r;
}

// ============================================================
// final MLP head, v3b: cooperative LDS-tiled (v3 + bounds fix).
// R10's absmax-0.89 failure was an LDS OOB: the emb staging loop
// iterated q<16 (4096 float4s) but only 64 nodes x 16 = 1024 exist,
// so nn=idx>>4 reached 255 on embs[64][..], stomping hids/w-arrays.
// Fixed: q<4. Everything else identical to v3: block=256 handles
// 64 nodes; emb staged coalesced float4; thread (node=t>>2, part=
// t&3) computes 16 hid entries then 10 outputs; accumulation order
// (i asc, j asc, fp32) identical to v1.
// ============================================================
__global__ __launch_bounds__(256) void mlp_head(
    const float* __restrict__ emb_in,
    const float* __restrict__ mw1, const float* __restrict__ mb1,
    const float* __restrict__ mw2, const float* __restrict__ mb2,
    float* __restrict__ outp, int n) {
  __shared__ float w1s[64 * 64];       // 16 KB  [i][j]
  __shared__ float w2s[64 * 40];       // 10 KB  [j][k]
  __shared__ float b1s[64];
  __shared__ float b2s[40];
  __shared__ float embs[64][66];       // 16.5 KB (padded)
  __shared__ float hids[64][66];       // 16.5 KB (padded)
  const int t = threadIdx.x;
  for (int i = t; i < 64 * 64; i += 256) w1s[i] = mw1[i];
  for (int i = t; i < 64 * 40; i += 256) w2s[i] = mw2[i];
  if (t < 64) b1s[t] = mb1[t];
  if (t < 40) b2s[t] = mb2[t];

  const int nodeBase = blockIdx.x * 64;
  // ---- stage emb: 64 nodes x 16 float4 = 1024 float4, coalesced ----
#pragma unroll
  for (int q = 0; q < 4; ++q) {
    int idx = q * 256 + t;             // float4 index 0..1023
    int nn = idx >> 4;                 // local node 0..63
    int ii = (idx & 15) * 4;           // feature 0..60
    int gn = min(nodeBase + nn, n - 1);
    float4 v = *(const float4*)&emb_in[(size_t)gn * 64 + ii];
    embs[nn][ii + 0] = v.x;
    embs[nn][ii + 1] = v.y;
    embs[nn][ii + 2] = v.z;
    embs[nn][ii + 3] = v.w;
  }
  __syncthreads();

  const int nl = t >> 2, p = t & 3;    // node-local, part
  // ---- hid: part p computes hid[nl][p*16 .. p*16+15] ----
  float acc[16];
#pragma unroll
  for (int j = 0; j < 16; ++j) acc[j] = b1s[p * 16 + j];
  for (int i = 0; i < 64; ++i) {
    float e = embs[nl][i];
    const float* wrow = &w1s[i * 64 + p * 16];
#pragma unroll
    for (int j = 0; j < 16; ++j) acc[j] += e * wrow[j];
  }
#pragma unroll
  for (int j = 0; j < 16; ++j)
    hids[nl][p * 16 + j] = acc[j] > 0.f ? acc[j] : 0.f;
  __syncthreads();

  // ---- out: part p computes out[k], k = p*10 .. p*10+9 ----
  const int node = nodeBase + nl;
  if (node < n) {
    float o[10];
#pragma unroll
    for (int k = 0; k < 10; ++k) o[k] = b2s[p * 10 + k];
    for (int j = 0; j < 64; ++j) {
      float hv = hids[nl][j];
      const float* wrow = &w2s[j * 40 + p * 10];
#pragma unroll
      for (int k = 0; k < 10; ++k) o[k] += hv * wrow[k];
    }
#pragma unroll
    for (int k = 0; k < 10; ++k)
      outp[(size_t)node * 40 + p * 10 + k] = o[k];
  }
}

extern "C" void kernel_launch(void* const* d_in, const int* in_sizes, int n_in,
                              void* d_out, int out_size, void* d_ws, size_t ws_size,
                              hipStream_t stream) {
  const float* x        = (const float*)d_in[0];
  const int*   ei       = (const int*)d_in[1];
  const float* W1       = (const float*)d_in[2];
  const float* att_src1 = (const float*)d_in[3];
  const float* att_dst1 = (const float*)d_in[4];
  const float* b1       = (const float*)d_in[5];
  const float* W2       = (const float*)d_in[6];
  const float* att_src2 = (const float*)d_in[7];
  const float* att_dst2 = (const float*)d_in[8];
  const float* b2       = (const float*)d_in[9];
  const float* mw1      = (const float*)d_in[10];
  const float* mb1      = (const float*)d_in[11];
  const float* mw2      = (const float*)d_in[12];
  const float* mb2      = (const float*)d_in[13];
  float* out = (float*)d_out;

  const int N = N_NODES, E = N_EDGES;
  char* base = (char*)d_ws;
  size_t o = 0;
  auto alloc = [&](size_t n_elems) {   // float-unit (4 B) allocator, 16B-aligned
    void* p = base + o;
    o = (o + n_elems * 4 + 15) & ~(size_t)15;
    return p;
  };
  int* cnt = (int*)alloc(N);
  int* cur = (int*)alloc(N);
  size_t zero_bytes = o;
  int*   offs  = (int*)alloc(N + 2);
  int*   bsum  = (int*)alloc(256);
  int*   bofs  = (int*)alloc(256);
  int*   ssort = (int*)alloc(E);
  float* h1e   = (float*)alloc((size_t)N * 256);
  float* asrc1 = (float*)alloc((size_t)N * 4);
  float* adst1 = (float*)alloc((size_t)N * 4);
  float* emb   = (float*)alloc((size_t)N * 64);
  float* asrc2 = (float*)alloc(N);
  float* adst2 = (float*)alloc(N);
  unsigned short* h1b = (unsigned short*)alloc((size_t)N * 128);  // N*256 bf16
  unsigned short* h2b = (unsigned short*)alloc((size_t)N * 32);   // N*64 bf16
  unsigned short* w1h = (unsigned short*)alloc(512 * 256 / 2);
  unsigned short* w1l = (unsigned short*)alloc(512 * 256 / 2);
  unsigned short* w2h = (unsigned short*)alloc(256 * 64 / 2);
  unsigned short* w2l = (unsigned short*)alloc(256 * 64 / 2);

  hipMemsetAsync(d_ws, 0, zero_bytes, stream);

  const int EB = (E + 255) / 256;

  // ---- build dst-sorted CSR + weight pre-split ----
  hist_k<<<EB, 256, 0, stream>>>(ei, cnt);
  scan1<<<SCAN_B, 256, 0, stream>>>(cnt, offs, bsum);
  scan2<<<1, 256, 0, stream>>>(bsum, bofs);
  scan3<<<SCAN_B, 256, 0, stream>>>(offs, bofs);
  scatter_k<<<EB, 256, 0, stream>>>(ei, offs, cur, ssort);
  wsplit_all<<<(16384 + 2048 + 255) / 256, 256, 0, stream>>>(W1, w1h, w1l,
                                                             W2, w2h, w2l);

  // ---- layer 1 ----
  dim3 g1((N + 127) / 128, 2);
  gemm1_fused<<<g1, 256, 0, stream>>>(x, w1h, w1l, att_src1, att_dst1,
                                      h1b, asrc1, adst1, N);
  agg_l1<<<(N + 7) / 8, 256, 0, stream>>>(offs, ssort, asrc1, adst1, h1b, b1,
                                          h1e, N);

  // ---- layer 2 ----
  dim3 g2((N + 127) / 128, 1);
  gemm2_fused<<<g2, 256, 0, stream>>>(h1e, w2h, w2l, att_src2, att_dst2,
                                      h2b, asrc2, adst2, N);
  agg_l2<<<(N + 15) / 16, 256, 0, stream>>>(offs, ssort, asrc2, adst2, h2b, b2,
                                            emb, N);

  // ---- MLP head ----
  mlp_head<<<(N + 63) / 64, 256, 0, stream>>>(emb, mw1, mb1, mw2, mb2, out, N);
}